// Round 16
// baseline (44.601 us; speedup 1.0000x reference)
//
#include <hip/hip_runtime.h>
#include <hip/hip_bf16.h>

#define NB 16     // batch
#define NN 512    // nodes
#define NF 64     // F_in == F_out
#define NE 16     // emb dim
#define NKF 192   // K*F_in
#define NNODE (NB*NN)   // 8192

typedef __hip_bfloat16 bf16;
typedef __attribute__((ext_vector_type(8))) short short8;
typedef __attribute__((ext_vector_type(4))) float f32x4;

typedef const __attribute__((address_space(1))) char gchar;
typedef __attribute__((address_space(3))) char lchar;

__device__ inline void gload16(const void* g, void* l) {
    __builtin_amdgcn_global_load_lds((gchar*)g, (lchar*)l, 16, 0, 0);
}

__device__ inline short f2bs(float f) {
    union { bf16 b; short s; } u; u.b = __float2bfloat16(f); return u.s;
}

// ---------------- k_pre: fused dinv + x(pack+transpose) + wcvt -------------
__global__ __launch_bounds__(256) void k_pre(
    const float* __restrict__ A, const float* __restrict__ x,
    const float* __restrict__ Wp, float* __restrict__ dis,
    bf16* __restrict__ xg, bf16* __restrict__ xT, bf16* __restrict__ Bt) {
    __shared__ float Ts[64][66];
    int bid = blockIdx.x, tid = threadIdx.x;
    if (bid < 2048) {
        int row = bid * 4 + (tid >> 6);
        int lane = tid & 63;
        const float4* a = (const float4*)(A + (size_t)row * NN);
        float s = 0.f;
        #pragma unroll
        for (int j = 0; j < 2; ++j) {
            float4 v = a[lane + 64 * j];
            s += fmaxf(v.x, 0.f) + fmaxf(v.y, 0.f) + fmaxf(v.z, 0.f) + fmaxf(v.w, 0.f);
        }
        #pragma unroll
        for (int off = 32; off >= 1; off >>= 1) s += __shfl_down(s, off, 64);
        if (lane == 0) dis[row] = rsqrtf(fmaxf(s + 1.0f, 1e-6f));
    } else if (bid < 2176) {
        int node0 = (bid - 2048) * 64;
        int r = tid >> 2, f0 = (tid & 3) * 16;
        const float* xp = x + (size_t)(node0 + r) * NF + f0;
        float v[16];
        #pragma unroll
        for (int i = 0; i < 16; ++i) v[i] = xp[i];
        short8 p0, p1;
        #pragma unroll
        for (int i = 0; i < 8; ++i) { p0[i] = f2bs(v[i]); p1[i] = f2bs(v[8 + i]); }
        *(short8*)&xg[(size_t)(node0 + r) * NKF + f0] = p0;
        *(short8*)&xg[(size_t)(node0 + r) * NKF + f0 + 8] = p1;
        #pragma unroll
        for (int i = 0; i < 4; ++i)
            *(float4*)&Ts[r][f0 + i * 4] = *(const float4*)(v + i * 4);
        __syncthreads();
        int f = tid >> 2, nq0 = (tid & 3) * 16;
        int b = node0 >> 9, nloc = node0 & (NN - 1);
        bf16* xt = xT + (size_t)(b * NF + f) * NN + nloc + nq0;
        #pragma unroll
        for (int h = 0; h < 2; ++h) {
            short8 o;
            #pragma unroll
            for (int i = 0; i < 8; ++i) o[i] = f2bs(Ts[nq0 + h * 8 + i][f]);
            *(short8*)&xt[h * 8] = o;
        }
    } else {
        int q = bid - 2176;                        // 0..47
        int e = q / 3, kt = q % 3;
        int r = tid >> 2, o0 = (tid & 3) * 16;
        const float* wp = Wp + (size_t)e * (NKF * NF) + (size_t)(kt * 64 + r) * NF + o0;
        #pragma unroll
        for (int i = 0; i < 4; ++i)
            *(float4*)&Ts[r][o0 + i * 4] = *(const float4*)(wp + i * 4);
        __syncthreads();
        int o = tid >> 2, r0 = (tid & 3) * 16;
        bf16* bt = Bt + (size_t)(e * 64 + o) * NKF + kt * 64 + r0;
        #pragma unroll
        for (int h = 0; h < 2; ++h) {
            short8 w;
            #pragma unroll
            for (int i = 0; i < 8; ++i) w[i] = f2bs(Ts[r0 + h * 8 + i][o]);
            *(short8*)&bt[h * 8] = w;
        }
    }
}

// ---------------- k_ahat: Ah[b][n][m] = bf16(dn*dm*(relu(A)+I)) ------------
__global__ __launch_bounds__(256) void k_ahat(
    const float* __restrict__ A, const float* __restrict__ dis,
    bf16* __restrict__ Ah) {
    int tid = threadIdx.x;
    int row = blockIdx.x * 4 + (tid >> 6);
    int m0 = (tid & 63) * 8;
    int b = row >> 9, n = row & (NN - 1);
    const float* db = dis + b * NN;
    float dn = db[n];
    const float* ap = A + (size_t)row * NN + m0;
    float4 a0 = *(const float4*)ap, a1 = *(const float4*)(ap + 4);
    float4 d0 = *(const float4*)(db + m0), d1 = *(const float4*)(db + m0 + 4);
    float av[8] = {a0.x, a0.y, a0.z, a0.w, a1.x, a1.y, a1.z, a1.w};
    float dm[8] = {d0.x, d0.y, d0.z, d0.w, d1.x, d1.y, d1.z, d1.w};
    short8 o;
    #pragma unroll
    for (int i = 0; i < 8; ++i) {
        float v = fmaxf(av[i], 0.f) + ((n == m0 + i) ? 1.f : 0.f);
        o[i] = f2bs(v * dn * dm[i]);
    }
    *(short8*)&Ah[(size_t)row * NN + m0] = o;
}

// ---------------- k_spmm0 (MFMA, K-chunk=128, R14-verified) ----------------
// y1 = Ah @ xT^T -> xg[:,64:128] + y1T
__global__ __launch_bounds__(256) void k_spmm0(
    const short* __restrict__ Ah, const short* __restrict__ Bsrc,
    bf16* __restrict__ xg, bf16* __restrict__ y1T) {
    __shared__ short As[4 * 2048];
    __shared__ short Xs[4 * 2048];
    __shared__ float Cs[64][66];
    int tid = threadIdx.x, lane = tid & 63, w = tid >> 6;
    int n0 = blockIdx.x * 64, b = blockIdx.y;
    const short* Ab = Ah + (size_t)b * NN * NN;
    const short* Xb = Bsrc + (size_t)b * NF * NN;

    int sr = tid >> 2;
    int p  = tid & 3;
    int cA = p ^ ((sr >> 1) & 3);

    int fr = lane & 15, ak = lane >> 4;

    f32x4 acc[4] = {};

    for (int kt = 0; kt < 4; ++kt) {
        __syncthreads();
        #pragma unroll
        for (int kc = 0; kc < 4; ++kc) {
            int col = kt * 128 + kc * 32 + cA * 8;
            gload16(Ab + (size_t)(n0 + sr) * NN + col, As + kc * 2048 + tid * 8);
            gload16(Xb + (size_t)sr * NN + col,        Xs + kc * 2048 + tid * 8);
        }
        __syncthreads();
        int rA = 16 * w + fr;
        int swA = (ak ^ ((rA >> 1) & 3)) * 8;
        #pragma unroll
        for (int kc = 0; kc < 4; ++kc) {
            short8 afr = *(const short8*)&As[kc * 2048 + rA * 32 + swA];
            #pragma unroll
            for (int j = 0; j < 4; ++j) {
                int colr = 16 * j + fr;
                short8 bfr = *(const short8*)&Xs[kc * 2048 + colr * 32 +
                                                 ((ak ^ ((colr >> 1) & 3)) * 8)];
                acc[j] = __builtin_amdgcn_mfma_f32_16x16x32_bf16(afr, bfr, acc[j], 0, 0, 0);
            }
        }
    }

    #pragma unroll
    for (int j = 0; j < 4; ++j)
        #pragma unroll
        for (int r = 0; r < 4; ++r)
            Cs[16 * w + 4 * ak + r][16 * j + fr] = acc[j][r];
    __syncthreads();

    int nl = tid >> 2, f0 = (tid & 3) * 16;
    size_t node = (size_t)b * NN + n0 + nl;
    float cv[16];
    #pragma unroll
    for (int i = 0; i < 16; ++i) cv[i] = Cs[nl][f0 + i];
    short8 p0, p1;
    #pragma unroll
    for (int i = 0; i < 8; ++i) { p0[i] = f2bs(cv[i]); p1[i] = f2bs(cv[8 + i]); }
    *(short8*)&xg[node * NKF + 64 + f0] = p0;
    *(short8*)&xg[node * NKF + 64 + f0 + 8] = p1;
    int f = tid >> 2, nq0 = (tid & 3) * 16;
    bf16* yt = y1T + (size_t)(b * NF + f) * NN + n0 + nq0;
    #pragma unroll
    for (int h = 0; h < 2; ++h) {
        short8 o;
        #pragma unroll
        for (int i = 0; i < 8; ++i) o[i] = f2bs(Cs[nq0 + h * 8 + i][f]);
        *(short8*)&yt[h * 8] = o;
    }
}

// ---------------- k_fuse: spmm1 + adaptive gemm + reduce -------------------
// Block = 64 nodes (grid 8 x 16). Phase 1: y2 = 2*(Ah@y1T^T) - x in regs.
// Phase 2: A-tile[64][192] = {xg cols 0:128 via gload16} U {y2 via ds_write}.
// Phase 3: for e in 0..15: stage Bt panel, pe = A@Bt_e^T, oacc += emb*(pe+bias).
__global__ __launch_bounds__(256) void k_fuse(
    const short* __restrict__ Ah, const short* __restrict__ y1T,
    const float* __restrict__ x, const short* __restrict__ xg,
    const short* __restrict__ Bt, const float* __restrict__ emb,
    const float* __restrict__ bp, float* __restrict__ out) {
    __shared__ short As[6 * 2048];   // 24KB: A-tile / spmm staging (subtiles 0-3)
    __shared__ short Bs[6 * 2048];   // 24KB: spmm X staging (0-3) then Bt panels
    __shared__ float Es[64 * NE];    // 4KB emb slice [node][e]
    __shared__ float Ps[NE * 64];    // 4KB bias [e][o]
    int tid = threadIdx.x, lane = tid & 63, w = tid >> 6;
    int n0 = blockIdx.x * 64, b = blockIdx.y;
    const short* Ab = Ah + (size_t)b * NN * NN;
    const short* Xb = y1T + (size_t)b * NF * NN;

    int sr = tid >> 2;
    int p  = tid & 3;
    int cA = p ^ ((sr >> 1) & 3);

    int fr = lane & 15, ak = lane >> 4;

    // ---- Phase 1: spmm1 (R14-verified K-chunk=128 body) ----
    f32x4 acc[4] = {};
    for (int kt = 0; kt < 4; ++kt) {
        __syncthreads();
        #pragma unroll
        for (int kc = 0; kc < 4; ++kc) {
            int col = kt * 128 + kc * 32 + cA * 8;
            gload16(Ab + (size_t)(n0 + sr) * NN + col, As + kc * 2048 + tid * 8);
            gload16(Xb + (size_t)sr * NN + col,        Bs + kc * 2048 + tid * 8);
        }
        __syncthreads();
        int rA = 16 * w + fr;
        int swA = (ak ^ ((rA >> 1) & 3)) * 8;
        #pragma unroll
        for (int kc = 0; kc < 4; ++kc) {
            short8 afr = *(const short8*)&As[kc * 2048 + rA * 32 + swA];
            #pragma unroll
            for (int j = 0; j < 4; ++j) {
                int colr = 16 * j + fr;
                short8 bfr = *(const short8*)&Bs[kc * 2048 + colr * 32 +
                                                 ((ak ^ ((colr >> 1) & 3)) * 8)];
                acc[j] = __builtin_amdgcn_mfma_f32_16x16x32_bf16(afr, bfr, acc[j], 0, 0, 0);
            }
        }
    }
    __syncthreads();   // all spmm LDS reads done; As/Bs free

    // ---- Phase 2: build A-tile ----
    // subtiles 0..3 (k=0..128) from xg, verified staging pattern
    #pragma unroll
    for (int kk = 0; kk < 4; ++kk)
        gload16(xg + (size_t)(b * NN + n0 + sr) * NKF + kk * 32 + cA * 8,
                As + kk * 2048 + tid * 8);
    // subtiles 4..5 (k=128..192) = y2 = 2*acc - x, scalar ds_write w/ swizzle
    #pragma unroll
    for (int j = 0; j < 4; ++j) {
        #pragma unroll
        for (int r = 0; r < 4; ++r) {
            int row = 16 * w + 4 * ak + r;       // node-local (C-layout row)
            int col = 16 * j + fr;               // feature 0..63
            float xv = x[((size_t)b * NN + n0 + row) * NF + col];
            short v = f2bs(2.f * acc[j][r] - xv);
            int kk   = 4 + (col >> 5);
            int c    = (col & 31) >> 3;
            int slot = c ^ ((row >> 1) & 3);
            As[kk * 2048 + row * 32 + slot * 8 + (fr & 7)] = v;
        }
    }
    // emb/bias -> LDS (layouts match global: [node][e], [e][o])
    {
        const float* eb = emb + (size_t)(b * NN + n0) * NE;
        #pragma unroll
        for (int i = 0; i < 4; ++i) Es[tid + i * 256] = eb[tid + i * 256];
        #pragma unroll
        for (int i = 0; i < 4; ++i) Ps[tid + i * 256] = bp[tid + i * 256];
    }
    __syncthreads();

    // hoist A-frags (constant across e)
    int arow = 16 * w + fr;
    int swA2 = (ak ^ ((arow >> 1) & 3)) * 8;
    short8 afr[6];
    #pragma unroll
    for (int kk = 0; kk < 6; ++kk)
        afr[kk] = *(const short8*)&As[kk * 2048 + arow * 32 + swA2];

    // ---- Phase 3: e-panel loop (R9 k_fused pattern, single-buffered) ----
    float oacc[4][4] = {};
    for (int e = 0; e < NE; ++e) {
        #pragma unroll
        for (int kk = 0; kk < 6; ++kk)
            gload16(Bt + (size_t)(e * 64 + sr) * NKF + kk * 32 + cA * 8,
                    Bs + kk * 2048 + tid * 8);
        __syncthreads();
        f32x4 pe[4] = {};
        #pragma unroll
        for (int kk = 0; kk < 6; ++kk) {
            #pragma unroll
            for (int j = 0; j < 4; ++j) {
                int brow = 16 * j + fr;
                short8 bfr = *(const short8*)&Bs[kk * 2048 + brow * 32 +
                                                 ((ak ^ ((brow >> 1) & 3)) * 8)];
                pe[j] = __builtin_amdgcn_mfma_f32_16x16x32_bf16(afr[kk], bfr, pe[j], 0, 0, 0);
            }
        }
        #pragma unroll
        for (int j = 0; j < 4; ++j) {
            float bv = Ps[e * 64 + 16 * j + fr];
            #pragma unroll
            for (int r = 0; r < 4; ++r) {
                int nl = 16 * w + 4 * ak + r;
                oacc[j][r] = fmaf(Es[nl * NE + e], pe[j][r] + bv, oacc[j][r]);
            }
        }
        __syncthreads();   // Bs free for next panel
    }

    // ---- write out ----
    #pragma unroll
    for (int j = 0; j < 4; ++j)
        #pragma unroll
        for (int r = 0; r < 4; ++r) {
            int node = b * NN + n0 + 16 * w + 4 * ak + r;
            out[(size_t)node * NF + 16 * j + fr] = oacc[j][r];
        }
}

extern "C" void kernel_launch(void* const* d_in, const int* in_sizes, int n_in,
                              void* d_out, int out_size, void* d_ws, size_t ws_size,
                              hipStream_t stream) {
    const float* x   = (const float*)d_in[0];   // [16,512,64]
    const float* emb = (const float*)d_in[1];   // [16,512,16]
    const float* A   = (const float*)d_in[2];   // [16,512,512]
    const float* Wp  = (const float*)d_in[3];   // [16,3,64,64]
    const float* bp  = (const float*)d_in[4];   // [16,64]
    float* out = (float*)d_out;                 // [16,512,64]

    float* ws  = (float*)d_ws;
    float* dis = ws;                                  // 8192 f32
    bf16*  xT  = (bf16*)(ws + 8192);                  // 16*64*512 bf16
    bf16*  y1T = (bf16*)(ws + 270336);                // same
    bf16*  xg  = (bf16*)(ws + 532480);                // 8192*192 bf16
    bf16*  Bt  = (bf16*)(ws + 1318912);               // 1024*192 bf16
    bf16*  Ah  = (bf16*)(ws + 1417216);               // 16*512*512 bf16
    // ws end: 3514368 f32 = 14.06 MB

    k_pre<<<2224, 256, 0, stream>>>(A, x, Wp, dis, xg, xT, Bt);
    k_ahat<<<2048, 256, 0, stream>>>(A, dis, Ah);
    dim3 g2(NN / 64, NB);
    k_spmm0<<<g2, 256, 0, stream>>>((const short*)Ah, (const short*)xT, xg, y1T);
    k_fuse<<<g2, 256, 0, stream>>>((const short*)Ah, (const short*)y1T, x,
                                   (const short*)xg, (const short*)Bt, emb, bp, out);
}

// Round 17
// 39.236 us; speedup vs baseline: 1.1367x; 1.1367x over previous
//
#include <hip/hip_runtime.h>
#include <hip/hip_bf16.h>

#define NB 16     // batch
#define NN 512    // nodes
#define NF 64     // F_in == F_out
#define NE 16     // emb dim
#define NKF 192   // K*F_in
#define NNODE (NB*NN)   // 8192

typedef __hip_bfloat16 bf16;
typedef __attribute__((ext_vector_type(8))) short short8;
typedef __attribute__((ext_vector_type(4))) float f32x4;

typedef const __attribute__((address_space(1))) char gchar;
typedef __attribute__((address_space(3))) char lchar;

__device__ inline void gload16(const void* g, void* l) {
    __builtin_amdgcn_global_load_lds((gchar*)g, (lchar*)l, 16, 0, 0);
}

__device__ inline short f2bs(float f) {
    union { bf16 b; short s; } u; u.b = __float2bfloat16(f); return u.s;
}

// ---------------- k_pre: fused dinv + x(pack+transpose) + wcvt -------------
__global__ __launch_bounds__(256) void k_pre(
    const float* __restrict__ A, const float* __restrict__ x,
    const float* __restrict__ Wp, float* __restrict__ dis,
    bf16* __restrict__ xg, bf16* __restrict__ xT, bf16* __restrict__ Bt) {
    __shared__ float Ts[64][66];
    int bid = blockIdx.x, tid = threadIdx.x;
    if (bid < 2048) {
        int row = bid * 4 + (tid >> 6);
        int lane = tid & 63;
        const float4* a = (const float4*)(A + (size_t)row * NN);
        float s = 0.f;
        #pragma unroll
        for (int j = 0; j < 2; ++j) {
            float4 v = a[lane + 64 * j];
            s += fmaxf(v.x, 0.f) + fmaxf(v.y, 0.f) + fmaxf(v.z, 0.f) + fmaxf(v.w, 0.f);
        }
        #pragma unroll
        for (int off = 32; off >= 1; off >>= 1) s += __shfl_down(s, off, 64);
        if (lane == 0) dis[row] = rsqrtf(fmaxf(s + 1.0f, 1e-6f));
    } else if (bid < 2176) {
        int node0 = (bid - 2048) * 64;
        int r = tid >> 2, f0 = (tid & 3) * 16;
        const float* xp = x + (size_t)(node0 + r) * NF + f0;
        float v[16];
        #pragma unroll
        for (int i = 0; i < 16; ++i) v[i] = xp[i];
        short8 p0, p1;
        #pragma unroll
        for (int i = 0; i < 8; ++i) { p0[i] = f2bs(v[i]); p1[i] = f2bs(v[8 + i]); }
        *(short8*)&xg[(size_t)(node0 + r) * NKF + f0] = p0;
        *(short8*)&xg[(size_t)(node0 + r) * NKF + f0 + 8] = p1;
        #pragma unroll
        for (int i = 0; i < 4; ++i)
            *(float4*)&Ts[r][f0 + i * 4] = *(const float4*)(v + i * 4);
        __syncthreads();
        int f = tid >> 2, nq0 = (tid & 3) * 16;
        int b = node0 >> 9, nloc = node0 & (NN - 1);
        bf16* xt = xT + (size_t)(b * NF + f) * NN + nloc + nq0;
        #pragma unroll
        for (int h = 0; h < 2; ++h) {
            short8 o;
            #pragma unroll
            for (int i = 0; i < 8; ++i) o[i] = f2bs(Ts[nq0 + h * 8 + i][f]);
            *(short8*)&xt[h * 8] = o;
        }
    } else {
        int q = bid - 2176;                        // 0..47
        int e = q / 3, kt = q % 3;
        int r = tid >> 2, o0 = (tid & 3) * 16;
        const float* wp = Wp + (size_t)e * (NKF * NF) + (size_t)(kt * 64 + r) * NF + o0;
        #pragma unroll
        for (int i = 0; i < 4; ++i)
            *(float4*)&Ts[r][o0 + i * 4] = *(const float4*)(wp + i * 4);
        __syncthreads();
        int o = tid >> 2, r0 = (tid & 3) * 16;
        bf16* bt = Bt + (size_t)(e * 64 + o) * NKF + kt * 64 + r0;
        #pragma unroll
        for (int h = 0; h < 2; ++h) {
            short8 w;
            #pragma unroll
            for (int i = 0; i < 8; ++i) w[i] = f2bs(Ts[r0 + h * 8 + i][o]);
            *(short8*)&bt[h * 8] = w;
        }
    }
}

// ---------------- k_ahat: Ah[b][n][m] = bf16(dn*dm*(relu(A)+I)) ------------
__global__ __launch_bounds__(256) void k_ahat(
    const float* __restrict__ A, const float* __restrict__ dis,
    bf16* __restrict__ Ah) {
    int tid = threadIdx.x;
    int row = blockIdx.x * 4 + (tid >> 6);
    int m0 = (tid & 63) * 8;
    int b = row >> 9, n = row & (NN - 1);
    const float* db = dis + b * NN;
    float dn = db[n];
    const float* ap = A + (size_t)row * NN + m0;
    float4 a0 = *(const float4*)ap, a1 = *(const float4*)(ap + 4);
    float4 d0 = *(const float4*)(db + m0), d1 = *(const float4*)(db + m0 + 4);
    float av[8] = {a0.x, a0.y, a0.z, a0.w, a1.x, a1.y, a1.z, a1.w};
    float dm[8] = {d0.x, d0.y, d0.z, d0.w, d1.x, d1.y, d1.z, d1.w};
    short8 o;
    #pragma unroll
    for (int i = 0; i < 8; ++i) {
        float v = fmaxf(av[i], 0.f) + ((n == m0 + i) ? 1.f : 0.f);
        o[i] = f2bs(v * dn * dm[i]);
    }
    *(short8*)&Ah[(size_t)row * NN + m0] = o;
}

// ---------------- k_spmm (MFMA, 32-row tiles, K-chunk=128) -----------------
// grid (16,16) = 256 blocks (1/CU). Block: C[32n x 64f] = Ah[32][512] @ Bsrc^T.
// Waves: rows 16*(w&1), cols 32*(w>>1). A-subtiles [32][32], X-subtiles [64][32].
template <int PASS>
__global__ __launch_bounds__(256) void k_spmm(
    const short* __restrict__ Ah, const short* __restrict__ Bsrc,
    const float* __restrict__ x, bf16* __restrict__ xg, bf16* __restrict__ y1T) {
    __shared__ short As[4 * 1024];    // 4 subtiles [32][32], 8KB
    __shared__ short Xs[4 * 2048];    // 4 subtiles [64][32], 16KB
    __shared__ float Cs[32][66];      // 8.4KB
    int tid = threadIdx.x, lane = tid & 63, w = tid >> 6;
    int n0 = blockIdx.x * 32, b = blockIdx.y;
    const short* Ab = Ah + (size_t)b * NN * NN;
    const short* Xb = Bsrc + (size_t)b * NF * NN;

    // X staging map (R14-verified): sr 0..63, chunk slot p, logical chunk cA
    int sr = tid >> 2;
    int p  = tid & 3;
    int cA = p ^ ((sr >> 1) & 3);
    // A staging map (32-row): 2 passes, pass h covers subtiles 2h + (tid>>7)
    int ar2 = (tid >> 2) & 31;
    int kq  = tid >> 7;                 // 0..1
    int cA2 = p ^ ((ar2 >> 1) & 3);

    int fr = lane & 15, ak = lane >> 4;

    f32x4 acc[2] = {};

    for (int kt = 0; kt < 4; ++kt) {    // K-chunk = 128
        __syncthreads();
        #pragma unroll
        for (int h = 0; h < 2; ++h) {
            int kc = h * 2 + kq;
            gload16(Ab + (size_t)(n0 + ar2) * NN + kt * 128 + kc * 32 + cA2 * 8,
                    As + h * 2048 + tid * 8);
        }
        #pragma unroll
        for (int kc = 0; kc < 4; ++kc)
            gload16(Xb + (size_t)sr * NN + kt * 128 + kc * 32 + cA * 8,
                    Xs + kc * 2048 + tid * 8);
        __syncthreads();
        int ra = 16 * (w & 1) + fr;
        int swA = (ak ^ ((ra >> 1) & 3)) * 8;
        #pragma unroll
        for (int kc = 0; kc < 4; ++kc) {
            short8 afr = *(const short8*)&As[kc * 1024 + ra * 32 + swA];
            #pragma unroll
            for (int j2 = 0; j2 < 2; ++j2) {
                int cr = 32 * (w >> 1) + 16 * j2 + fr;
                short8 bfr = *(const short8*)&Xs[kc * 2048 + cr * 32 +
                                                 ((ak ^ ((cr >> 1) & 3)) * 8)];
                acc[j2] = __builtin_amdgcn_mfma_f32_16x16x32_bf16(afr, bfr, acc[j2], 0, 0, 0);
            }
        }
    }

    // C-frag: row 16*(w&1) + 4*ak + r, col 32*(w>>1) + 16*j2 + fr
    #pragma unroll
    for (int j2 = 0; j2 < 2; ++j2)
        #pragma unroll
        for (int r = 0; r < 4; ++r)
            Cs[16 * (w & 1) + 4 * ak + r][32 * (w >> 1) + 16 * j2 + fr] = acc[j2][r];
    __syncthreads();

    // epilogue: 32 n x 64 f, one short8 per thread for xg
    int nl = tid >> 3, f0 = (tid & 7) * 8;
    size_t node = (size_t)b * NN + n0 + nl;
    float cv[8];
    #pragma unroll
    for (int i = 0; i < 8; ++i) cv[i] = Cs[nl][f0 + i];
    if (PASS == 0) {
        short8 pk;
        #pragma unroll
        for (int i = 0; i < 8; ++i) pk[i] = f2bs(cv[i]);
        *(short8*)&xg[node * NKF + 64 + f0] = pk;
        // transposed write y1T[b][f][n]: f = tid>>2 (0..63), nq0 = (tid&3)*8
        int f = tid >> 2, nq0 = (tid & 3) * 8;
        short8 o;
        #pragma unroll
        for (int i = 0; i < 8; ++i) o[i] = f2bs(Cs[nq0 + i][f]);
        *(short8*)&y1T[(size_t)(b * NF + f) * NN + n0 + nq0] = o;
    } else {
        const float* xp = x + node * NF + f0;
        short8 pk;
        #pragma unroll
        for (int i = 0; i < 8; ++i) pk[i] = f2bs(2.f * cv[i] - xp[i]);
        *(short8*)&xg[node * NKF + 128 + f0] = pk;
    }
}

// ---------------- k_gemm: t = Xg @ Bt^T (bf16 MFMA, 128x128 tile, R7/R14) --
__global__ __launch_bounds__(256) void k_gemm(
    const short* __restrict__ xg, const short* __restrict__ Bt,
    bf16* __restrict__ t) {
    __shared__ short As[128 * 32];
    __shared__ short Bs[128 * 32];
    int tid = threadIdx.x;
    int lane = tid & 63;
    int w = tid >> 6;
    int n0 = blockIdx.x * 128;
    int c0 = blockIdx.y * 128;

    int rA0 = tid >> 2;
    int p   = tid & 3;
    int cA  = p ^ ((rA0 >> 1) & 3);

    int fr = lane & 15;
    int fc = ((lane >> 4) ^ ((fr >> 1) & 3)) * 8;

    f32x4 acc[4][4] = {};

    for (int kt = 0; kt < 6; ++kt) {
        __syncthreads();
        gload16(xg + (size_t)(n0 + rA0) * NKF + kt * 32 + cA * 8, As + tid * 8);
        gload16(xg + (size_t)(n0 + rA0 + 64) * NKF + kt * 32 + cA * 8, As + 2048 + tid * 8);
        gload16(Bt + (size_t)(c0 + rA0) * NKF + kt * 32 + cA * 8, Bs + tid * 8);
        gload16(Bt + (size_t)(c0 + rA0 + 64) * NKF + kt * 32 + cA * 8, Bs + 2048 + tid * 8);
        __syncthreads();

        int wr = w >> 1, wc = w & 1;
        short8 a[4], bfr[4];
        #pragma unroll
        for (int i = 0; i < 4; ++i)
            a[i] = *(const short8*)&As[(wr * 64 + i * 16 + fr) * 32 + fc];
        #pragma unroll
        for (int j = 0; j < 4; ++j)
            bfr[j] = *(const short8*)&Bs[(wc * 64 + j * 16 + fr) * 32 + fc];
        #pragma unroll
        for (int i = 0; i < 4; ++i)
            #pragma unroll
            for (int j = 0; j < 4; ++j)
                acc[i][j] = __builtin_amdgcn_mfma_f32_16x16x32_bf16(a[i], bfr[j], acc[i][j], 0, 0, 0);
    }

    int wr = w >> 1, wc = w & 1;
    #pragma unroll
    for (int i = 0; i < 4; ++i) {
        #pragma unroll
        for (int j = 0; j < 4; ++j) {
            #pragma unroll
            for (int r = 0; r < 4; ++r) {
                int m = n0 + wr * 64 + i * 16 + (lane >> 4) * 4 + r;
                int cc = c0 + wc * 64 + j * 16 + (lane & 15);
                t[(size_t)m * 1024 + cc] = __float2bfloat16(acc[i][j][r]);
            }
        }
    }
}

// ---------------- k_reduce: out = sum_e emb*(t + bias) (R7/R14) ------------
__global__ void k_reduce(const bf16* __restrict__ t, const float* __restrict__ emb,
                         const float* __restrict__ bp, float* __restrict__ out) {
    int gid = blockIdx.x * 256 + threadIdx.x;      // 0..524287
    int node = gid >> 6, o = gid & 63;
    float s = 0.f;
    #pragma unroll
    for (int e = 0; e < NE; ++e) {
        float tv = __bfloat162float(t[(size_t)node * 1024 + e * 64 + o]);
        s = fmaf(emb[(size_t)node * NE + e], tv + bp[e * 64 + o], s);
    }
    out[gid] = s;
}

extern "C" void kernel_launch(void* const* d_in, const int* in_sizes, int n_in,
                              void* d_out, int out_size, void* d_ws, size_t ws_size,
                              hipStream_t stream) {
    const float* x   = (const float*)d_in[0];   // [16,512,64]
    const float* emb = (const float*)d_in[1];   // [16,512,16]
    const float* A   = (const float*)d_in[2];   // [16,512,512]
    const float* Wp  = (const float*)d_in[3];   // [16,3,64,64]
    const float* bp  = (const float*)d_in[4];   // [16,64]
    float* out = (float*)d_out;                 // [16,512,64]

    float* ws  = (float*)d_ws;
    float* dis = ws;                                  // 8192 f32
    bf16*  xT  = (bf16*)(ws + 8192);                  // 16*64*512 bf16
    bf16*  y1T = (bf16*)(ws + 270336);                // same
    bf16*  xg  = (bf16*)(ws + 532480);                // 8192*192 bf16
    bf16*  Bt  = (bf16*)(ws + 1318912);               // 1024*192 bf16
    bf16*  Ah  = (bf16*)(ws + 1417216);               // 16*512*512 bf16
    bf16*  t   = (bf16*)(ws + 3514368);               // 8192*1024 bf16
    // ws end: 7708672 f32 = 30.8 MB

    k_pre<<<2224, 256, 0, stream>>>(A, x, Wp, dis, xg, xT, Bt);
    k_ahat<<<2048, 256, 0, stream>>>(A, dis, Ah);
    dim3 g2(NN / 32, NB);
    k_spmm<0><<<g2, 256, 0, stream>>>((const short*)Ah, (const short*)xT, x, xg, y1T);
    k_spmm<1><<<g2, 256, 0, stream>>>((const short*)Ah, (const short*)y1T, x, xg, y1T);
    dim3 gg(NNODE / 128, 8);
    k_gemm<<<gg, 256, 0, stream>>>((const short*)xg, (const short*)Bt, t);
    k_reduce<<<NNODE * NF / 256, 256, 0, stream>>>(t, emb, bp, out);
}